// Round 2
// baseline (20529.396 us; speedup 1.0000x reference)
//
#include <hip/hip_runtime.h>
#include <hip/hip_fp16.h>
#include <hip/hip_bf16.h>
#include <math.h>

// ---------------- constants ----------------
constexpr int   N_   = 2048;
constexpr int   DF_  = 256;
constexpr int   J_   = 8;
constexpr int   ELLW_= 64;
constexpr int   M_   = 256;          // Chebyshev terms (degree 255)
constexpr float H_   = 1.01f;        // domain half-width  ([-0.01, 2.01])
constexpr float C0_  = 1.0f;         // domain center
constexpr float AF_  = 0.34657359027997264f;   // A = 3*ln(2)/6
constexpr float PI_F = 3.14159265358979323846f;

typedef float f4v __attribute__((ext_vector_type(4)));
typedef __attribute__((ext_vector_type(8))) short bf16x8;
typedef __attribute__((ext_vector_type(4))) float f32x4;
using u16 = unsigned short;

__device__ __forceinline__ u16 f2bf(float v) {
    __hip_bfloat16 h = __float2bfloat16(v);
    union { __hip_bfloat16 b; u16 u; } cv; cv.b = h; return cv.u;
}

// ---------------- filter functions ----------------
__device__ __forceinline__ float g_hat_f(float x) {
    float val = 0.5f + 0.5f * cosf(2.f * PI_F * (x / AF_ + 0.5f));
    return (x <= 0.f && x > -AF_) ? val : 0.f;
}
__device__ __forceinline__ float wavelet_f(float lamb, int j) {
    float lmin = expf(AF_ * ((j - 1) / 3.0f - 1.0f));
    float lam  = fmaxf(lamb, lmin);
    return g_hat_f(logf(lam) - AF_ * (j - 1) / 3.0f);
}
__device__ __forceinline__ float filter_eval(float lamb, int jf) {
    if (jf == 0) {
        float g3 = 0.f;
        for (int j = 2; j <= 8; ++j) { float w = wavelet_f(lamb, j); g3 += w * w; }
        return sqrtf(fmaxf(1.5f - g3, 0.f));
    }
    return wavelet_f(lamb, jf + 1);
}

// ---------------- setup kernels ----------------
__global__ __launch_bounds__(256) void deg_kernel(const float* __restrict__ W,
                                                  float* __restrict__ dh,
                                                  float* __restrict__ dr) {
    int i = blockIdx.x, t = threadIdx.x;
    const float4* row = (const float4*)(W + (size_t)i * N_);
    float s = 0.f;
    for (int c = t; c < N_ / 4; c += 256) { float4 v = row[c]; s += v.x + v.y + v.z + v.w; }
    __shared__ float red[256];
    red[t] = s; __syncthreads();
    for (int o = 128; o; o >>= 1) { if (t < o) red[t] += red[t + o]; __syncthreads(); }
    if (t == 0) {
        float deg = red[0];
        float dhi = 1.f / sqrtf(fmaxf(deg, 1.f));
        dh[i] = dhi;
        dr[i] = (dhi * dhi * deg - C0_) / H_;
    }
}

__global__ __launch_bounds__(64) void ell_kernel(const float* __restrict__ W,
                                                 const float* __restrict__ dh,
                                                 int* __restrict__ cnt,
                                                 int* __restrict__ cols,
                                                 float* __restrict__ vals) {
    int i = blockIdx.x, lane = threadIdx.x;
    const float* row = W + (size_t)i * N_;
    unsigned long long lt = (1ull << lane) - 1ull;
    int base = 0;
    float dhi = dh[i];
    for (int c = 0; c < N_; c += 64) {
        float v = row[c + lane];
        unsigned long long m = __ballot(v != 0.f);
        if (v != 0.f) {
            int pos = base + __popcll(m & lt);
            if (pos < ELLW_) {
                cols[i * ELLW_ + pos] = c + lane;
                vals[i * ELLW_ + pos] = dhi * dh[c + lane] / H_;
            }
        }
        base += __popcll(m);
    }
    if (lane == 0) cnt[i] = base < ELLW_ ? base : ELLW_;
}

__global__ __launch_bounds__(256) void coef_kernel(float* __restrict__ coefs) {
    __shared__ float fv[J_][M_];
    int t = threadIdx.x;
    float theta = PI_F * (t + 0.5f) / M_;
    float lam = C0_ + H_ * cosf(theta);
    for (int j = 0; j < J_; ++j) fv[j][t] = filter_eval(lam, j);
    __syncthreads();
    for (int j = 0; j < J_; ++j) {
        float s = 0.f;
        for (int i = 0; i < M_; ++i)
            s += fv[j][i] * cosf(PI_F * t * (i + 0.5f) / M_);
        coefs[j * M_ + t] = s * ((t == 0 ? 1.f : 2.f) / M_);
    }
}

__global__ __launch_bounds__(256) void init_T(float* __restrict__ T0, float* __restrict__ T1,
                                              __half* __restrict__ S0, __half* __restrict__ S1,
                                              const int* __restrict__ cnt, const int* __restrict__ cols,
                                              const float* __restrict__ vals, const float* __restrict__ dr) {
    int i = blockIdx.x, t = threadIdx.x;
    size_t ro = (size_t)i * N_;
    for (int c = t * 4; c < N_; c += 1024) {
        *(float4*)(T0 + ro + c) = float4{0, 0, 0, 0};
        *(float4*)(T1 + ro + c) = float4{0, 0, 0, 0};
        if (S0) { *(ushort4*)(S0 + ro + c) = ushort4{0, 0, 0, 0};
                  *(ushort4*)(S1 + ro + c) = ushort4{0, 0, 0, 0}; }
    }
    __syncthreads();
    int n = cnt[i];
    if (t < n) {
        int c = cols[i * ELLW_ + t];
        float v = -vals[i * ELLW_ + t];
        T1[ro + c] = v;
        if (S1) S1[ro + c] = __float2half(v);
    }
    if (t == 0) {
        T0[ro + i] = 1.f;
        T1[ro + i] = dr[i];
        if (S0) { S0[ro + i] = __float2half(1.f); S1[ro + i] = __float2half(dr[i]); }
    }
}

// ------- XCD-striped Chebyshev step: Tnext = 2*Ltilde*X - Tprev, gather from fp16 X ------
// colgroup = blockIdx.x % 8 -> all blocks touching a 256-col stripe land on one XCD
// (round-robin dispatch), so the fp16 X-stripe (1 MB) stays L2-resident.
__global__ __launch_bounds__(256) void cheb_stripe(const __half* __restrict__ Xh,
                                                   const float* __restrict__ Tprev,
                                                   float* __restrict__ Tnext,
                                                   __half* __restrict__ slot,
                                                   const int* __restrict__ cnt,
                                                   const int* __restrict__ cols,
                                                   const float* __restrict__ vals,
                                                   const float* __restrict__ dr) {
    int cg   = blockIdx.x & 7;
    int rb   = blockIdx.x >> 3;
    int tr   = threadIdx.x >> 6;
    int lane = threadIdx.x & 63;
    int i    = rb * 4 + tr;
    int col  = cg * 256 + lane * 4;
    __shared__ int   scols[4][ELLW_];
    __shared__ float svals[4][ELLW_];
    scols[tr][lane] = cols[i * ELLW_ + lane];
    svals[tr][lane] = vals[i * ELLW_ + lane];
    __syncthreads();
    int n = cnt[i];
    float ax = 0.f, ay = 0.f, az = 0.f, aw = 0.f;
    for (int e = 0; e < n; ++e) {
        int   c = scols[tr][e];
        float v = svals[tr][e];
        const __half2* xp = (const __half2*)(Xh + (size_t)c * N_ + col);
        __half2 h0 = xp[0], h1 = xp[1];
        float2 f0 = __half22float2(h0), f1 = __half22float2(h1);
        ax -= v * f0.x; ay -= v * f0.y; az -= v * f1.x; aw -= v * f1.y;
    }
    {
        const __half2* xp = (const __half2*)(Xh + (size_t)i * N_ + col);
        __half2 h0 = xp[0], h1 = xp[1];
        float2 f0 = __half22float2(h0), f1 = __half22float2(h1);
        float d = dr[i];
        ax += d * f0.x; ay += d * f0.y; az += d * f1.x; aw += d * f1.y;
    }
    size_t po = (size_t)i * N_ + col;
    f4v tp = __builtin_nontemporal_load((const f4v*)(Tprev + po));
    f4v o;
    o[0] = 2.f * ax - tp[0]; o[1] = 2.f * ay - tp[1];
    o[2] = 2.f * az - tp[2]; o[3] = 2.f * aw - tp[3];
    __builtin_nontemporal_store(o, (f4v*)(Tnext + po));
    __half2* sp = (__half2*)(slot + po);
    sp[0] = __floats2half2_rn(o[0], o[1]);
    sp[1] = __floats2half2_rn(o[2], o[3]);
}

// ---------------- legacy fp32-gather step (fallback when workspace is tiny) -------------
__global__ __launch_bounds__(256) void cheb_step(const float* __restrict__ X,
                                                 const float* __restrict__ Tprev,
                                                 float* __restrict__ Tnext,
                                                 __half* __restrict__ slot,
                                                 const int* __restrict__ cnt,
                                                 const int* __restrict__ cols,
                                                 const float* __restrict__ vals,
                                                 const float* __restrict__ dr) {
    int i = blockIdx.x;
    int col = blockIdx.y * 1024 + threadIdx.x * 4;
    __shared__ int   scols[ELLW_];
    __shared__ float svals[ELLW_];
    int n = cnt[i];
    if (threadIdx.x < ELLW_) {
        scols[threadIdx.x] = cols[i * ELLW_ + threadIdx.x];
        svals[threadIdx.x] = vals[i * ELLW_ + threadIdx.x];
    }
    __syncthreads();
    float4 acc = {0, 0, 0, 0};
    for (int e = 0; e < n; ++e) {
        const float4 xv = *(const float4*)(X + (size_t)scols[e] * N_ + col);
        float v = svals[e];
        acc.x -= v * xv.x; acc.y -= v * xv.y; acc.z -= v * xv.z; acc.w -= v * xv.w;
    }
    float4 xs = *(const float4*)(X + (size_t)i * N_ + col);
    float d = dr[i];
    acc.x += d * xs.x; acc.y += d * xs.y; acc.z += d * xs.z; acc.w += d * xs.w;
    float4 tp = *(const float4*)(Tprev + (size_t)i * N_ + col);
    float4 o;
    o.x = 2.f * acc.x - tp.x; o.y = 2.f * acc.y - tp.y;
    o.z = 2.f * acc.z - tp.z; o.w = 2.f * acc.w - tp.w;
    *(float4*)(Tnext + (size_t)i * N_ + col) = o;
    if (slot) {
        __half2* sp = (__half2*)(slot + (size_t)i * N_ + col);
        sp[0] = __floats2half2_rn(o.x, o.y);
        sp[1] = __floats2half2_rn(o.z, o.w);
    }
}

// ---------------- group reduction:  G_j += sum_s b_{j,k0+s} * T_slot_s ----------------
__global__ __launch_bounds__(256) void reduce_half(const __half* __restrict__ slots, int nslot,
                                                   const float* __restrict__ coefs, int k0, int initG,
                                                   float* __restrict__ G) {
    const size_t NSQ = (size_t)N_ * N_;
    size_t idx = ((size_t)blockIdx.x * 256 + threadIdx.x) * 4;
    __shared__ float sc[J_ * 64];
    for (int x = threadIdx.x; x < J_ * nslot; x += 256) {
        int j = x / nslot, s = x - j * nslot;
        sc[j * 64 + s] = coefs[j * M_ + k0 + s];
    }
    __syncthreads();
    float4 g[J_];
#pragma unroll
    for (int j = 0; j < J_; ++j)
        g[j] = initG ? float4{0, 0, 0, 0} : *(const float4*)(G + (size_t)j * NSQ + idx);
    for (int s = 0; s < nslot; ++s) {
        const __half2* hp = (const __half2*)(slots + (size_t)s * NSQ + idx);
        float2 f0 = __half22float2(hp[0]);
        float2 f1 = __half22float2(hp[1]);
#pragma unroll
        for (int j = 0; j < J_; ++j) {
            float c = sc[j * 64 + s];
            g[j].x += c * f0.x; g[j].y += c * f0.y;
            g[j].z += c * f1.x; g[j].w += c * f1.y;
        }
    }
#pragma unroll
    for (int j = 0; j < J_; ++j) *(float4*)(G + (size_t)j * NSQ + idx) = g[j];
}

__global__ __launch_bounds__(256) void reduce_f32(const float* __restrict__ T,
                                                  const float* __restrict__ coefs, int k, int initG,
                                                  float* __restrict__ G) {
    const size_t NSQ = (size_t)N_ * N_;
    size_t idx = ((size_t)blockIdx.x * 256 + threadIdx.x) * 4;
    float4 tv = *(const float4*)(T + idx);
#pragma unroll
    for (int j = 0; j < J_; ++j) {
        float c = coefs[j * M_ + k];
        float* gp = G + (size_t)j * NSQ + idx;
        float4 g = initG ? float4{0, 0, 0, 0} : *(float4*)gp;
        g.x += c * tv.x; g.y += c * tv.y; g.z += c * tv.z; g.w += c * tv.w;
        *(float4*)gp = g;
    }
}

// ---------------- fp32 -> bf16 convert ----------------
__global__ __launch_bounds__(256) void convert_bf16(const float* __restrict__ src,
                                                    u16* __restrict__ dst) {
    size_t i4 = ((size_t)blockIdx.x * 256 + threadIdx.x) * 4;
    float4 v = *(const float4*)(src + i4);
    ushort4 o;
    o.x = f2bf(v.x); o.y = f2bf(v.y); o.z = f2bf(v.z); o.w = f2bf(v.w);
    *(ushort4*)(dst + i4) = o;
}

// ---------------- MFMA bf16 GEMM with fused |.| + column-sum epilogue ----------------
// C = Gb[16384 x 2048] * B.  MODE 0: B = fb (2048 x 256), store U1b bf16 [node][j*256+d],
// colsum1[j*256+d].  MODE 1: B = U1b (2048 x 2048), colsum2[(b*8+j)*256+d].
template <int MODE>
__global__ __launch_bounds__(256) void mfma_gemm(const u16* __restrict__ A,
                                                 const u16* __restrict__ B,
                                                 u16* __restrict__ Uout,
                                                 float* __restrict__ colsum) {
    constexpr int LDK = 72;                       // 64 + 8 pad (16B-aligned rows)
    constexpr int NB  = (MODE == 0) ? 256 : 2048; // B row width
    __shared__ u16 As[128 * LDK];
    __shared__ u16 Bs[128 * LDK];                 // transposed: [n][k]
    int tid = threadIdx.x;
    int w = tid >> 6, lane = tid & 63;
    int wr = w >> 1, wc = w & 1;
    int gm0 = blockIdx.y * 128, n0 = blockIdx.x * 128;
    f32x4 acc[4][4];
#pragma unroll
    for (int mf = 0; mf < 4; ++mf)
#pragma unroll
        for (int nf = 0; nf < 4; ++nf) acc[mf][nf] = (f32x4){0.f, 0.f, 0.f, 0.f};

    int r = tid >> 1, h = tid & 1;
    int kk = tid >> 2, seg = tid & 3;
    for (int k0 = 0; k0 < 2048; k0 += 64) {
        // stage A tile [128][64] (k-contiguous rows)
        const u16* ap = A + (size_t)(gm0 + r) * 2048 + k0 + h * 32;
        u16* as = As + r * LDK + h * 32;
        *(uint4*)(as + 0)  = *(const uint4*)(ap + 0);
        *(uint4*)(as + 8)  = *(const uint4*)(ap + 8);
        *(uint4*)(as + 16) = *(const uint4*)(ap + 16);
        *(uint4*)(as + 24) = *(const uint4*)(ap + 24);
        // stage B tile transposed -> Bs[n][k]
        const u16* bp = B + (size_t)(k0 + kk) * NB + n0 + seg * 32;
        uint4 q0 = *(const uint4*)(bp + 0);
        uint4 q1 = *(const uint4*)(bp + 8);
        uint4 q2 = *(const uint4*)(bp + 16);
        uint4 q3 = *(const uint4*)(bp + 24);
        u16* bs = Bs + (seg * 32) * LDK + kk;
#define WR8(Q, base) \
        bs[(base + 0) * LDK] = (u16)(Q.x);       bs[(base + 1) * LDK] = (u16)(Q.x >> 16); \
        bs[(base + 2) * LDK] = (u16)(Q.y);       bs[(base + 3) * LDK] = (u16)(Q.y >> 16); \
        bs[(base + 4) * LDK] = (u16)(Q.z);       bs[(base + 5) * LDK] = (u16)(Q.z >> 16); \
        bs[(base + 6) * LDK] = (u16)(Q.w);       bs[(base + 7) * LDK] = (u16)(Q.w >> 16);
        WR8(q0, 0) WR8(q1, 8) WR8(q2, 16) WR8(q3, 24)
#undef WR8
        __syncthreads();
#pragma unroll
        for (int s = 0; s < 2; ++s) {
            int krd = s * 32 + (lane >> 4) * 8;
            bf16x8 af[4], bfv[4];
#pragma unroll
            for (int mf = 0; mf < 4; ++mf)
                af[mf] = *(const bf16x8*)(As + (wr * 64 + mf * 16 + (lane & 15)) * LDK + krd);
#pragma unroll
            for (int nf = 0; nf < 4; ++nf)
                bfv[nf] = *(const bf16x8*)(Bs + (wc * 64 + nf * 16 + (lane & 15)) * LDK + krd);
#pragma unroll
            for (int mf = 0; mf < 4; ++mf)
#pragma unroll
                for (int nf = 0; nf < 4; ++nf)
                    acc[mf][nf] = __builtin_amdgcn_mfma_f32_16x16x32_bf16(
                        af[mf], bfv[nf], acc[mf][nf], 0, 0, 0);
        }
        __syncthreads();
    }
    // epilogue: C layout col = lane&15, row = (lane>>4)*4 + reg
    int j = gm0 >> 11;
#pragma unroll
    for (int nf = 0; nf < 4; ++nf) {
        float cs = 0.f;
#pragma unroll
        for (int mf = 0; mf < 4; ++mf) {
#pragma unroll
            for (int rr = 0; rr < 4; ++rr) {
                float val = fabsf(acc[mf][nf][rr]);
                cs += val;
                if (MODE == 0) {
                    int gm = gm0 + wr * 64 + mf * 16 + (lane >> 4) * 4 + rr;
                    int i = gm & (N_ - 1);
                    int d = n0 + wc * 64 + nf * 16 + (lane & 15);
                    Uout[(size_t)i * 2048 + j * 256 + d] = f2bf(val);
                }
            }
        }
        cs += __shfl_xor(cs, 16);
        cs += __shfl_xor(cs, 32);
        if ((lane >> 4) == 0) {
            int colg = n0 + wc * 64 + nf * 16 + lane;
            if (MODE == 0) atomicAdd(&colsum[j * 256 + colg], cs);
            else atomicAdd(&colsum[(((colg >> 8) * 8 + j) << 8) + (colg & 255)], cs);
        }
    }
}

__global__ __launch_bounds__(256) void fmean_kernel(const float* __restrict__ f, float* __restrict__ out) {
    int d = threadIdx.x;
    float s = 0.f;
    for (int n = 0; n < N_; ++n) s += f[(size_t)n * DF_ + d];
    out[d] = s * (1.f / N_);
}

__global__ __launch_bounds__(256) void finalize_kernel(const float* __restrict__ sum1,
                                                       const float* __restrict__ sum2,
                                                       float* __restrict__ out) {
    int idx = blockIdx.x * 256 + threadIdx.x;
    if (idx < 2048)  out[256 + idx]  = sum1[idx] * (1.f / N_);
    if (idx < 16384) out[2304 + idx] = sum2[idx] * (1.f / N_);
}

// ---------------- host orchestration ----------------
extern "C" void kernel_launch(void* const* d_in, const int* in_sizes, int n_in,
                              void* d_out, int out_size, void* d_ws, size_t ws_size,
                              hipStream_t stream) {
    (void)in_sizes; (void)n_in;
    const float* W = (const float*)d_in[0];
    const float* f = (const float*)d_in[1];
    float* out = (float*)d_out;
    char* base = (char*)d_ws;
    size_t off = 0;
    auto take = [&](size_t bytes) -> char* {
        off = (off + 255) & ~(size_t)255;
        char* p = base + off; off += bytes; return p;
    };
    const size_t NSQ = (size_t)N_ * N_;
    float* dh    = (float*)take((size_t)N_ * 4);
    float* dr    = (float*)take((size_t)N_ * 4);
    int*   cnt   = (int*)take((size_t)N_ * 4);
    int*   cols  = (int*)take((size_t)N_ * ELLW_ * 4);
    float* vals  = (float*)take((size_t)N_ * ELLW_ * 4);
    float* coefs = (float*)take((size_t)J_ * M_ * 4);
    float* sum1  = (float*)take(2048 * 4);
    float* sum2  = (float*)take(16384 * 4);
    float* T0 = (float*)take(NSQ * 4);
    float* T1 = (float*)take(NSQ * 4);
    float* T2 = (float*)take(NSQ * 4);
    float* G  = (float*)take(NSQ * 4 * J_);
    u16*   Gb  = (u16*)take(NSQ * 2 * J_);
    u16*   U1b = (u16*)take((size_t)N_ * 2048 * 2);
    u16*   fb  = (u16*)take((size_t)N_ * DF_ * 2);
    off = (off + 255) & ~(size_t)255;
    if (ws_size < off) {
        hipMemsetAsync(d_out, 0, (size_t)out_size * 4, stream);
        return;
    }
    const size_t slotBytes = NSQ * 2;
    long long rem = (long long)ws_size - (long long)off;
    int g = (int)(rem / (long long)slotBytes);
    if (g > 64) g = 64;
    __half* slots = (__half*)(base + off);
    bool f16path = g >= 3;

    deg_kernel<<<N_, 256, 0, stream>>>(W, dh, dr);
    ell_kernel<<<N_, 64, 0, stream>>>(W, dh, cnt, cols, vals);
    coef_kernel<<<1, 256, 0, stream>>>(coefs);
    hipMemsetAsync(sum1, 0, 2048 * 4, stream);
    hipMemsetAsync(sum2, 0, 16384 * 4, stream);
    init_T<<<N_, 256, 0, stream>>>(T0, T1,
                                   f16path ? slots : (__half*)nullptr,
                                   f16path ? slots + NSQ : (__half*)nullptr,
                                   cnt, cols, vals, dr);
    float* Tb[3] = {T0, T1, T2};
    if (f16path) {
        __half* slotX = slots + NSQ;   // fp16 copy of T1
        int group_start = 0;
        for (int k = 2; k < M_; ++k) {
            __half* slotW = slots + (size_t)(k - group_start) * NSQ;
            cheb_stripe<<<4096, 256, 0, stream>>>(
                slotX, Tb[(k - 2) % 3], Tb[k % 3], slotW, cnt, cols, vals, dr);
            slotX = slotW;
            if (k - group_start + 1 == g || k == M_ - 1) {
                reduce_half<<<4096, 256, 0, stream>>>(slots, k - group_start + 1, coefs,
                                                      group_start, group_start == 0 ? 1 : 0, G);
                group_start = k + 1;
            }
        }
    } else {
        reduce_f32<<<4096, 256, 0, stream>>>(T0, coefs, 0, 1, G);
        reduce_f32<<<4096, 256, 0, stream>>>(T1, coefs, 1, 0, G);
        for (int k = 2; k < M_; ++k) {
            cheb_step<<<dim3(N_, 2), 256, 0, stream>>>(
                Tb[(k - 1) % 3], Tb[(k - 2) % 3], Tb[k % 3],
                (__half*)nullptr, cnt, cols, vals, dr);
            reduce_f32<<<4096, 256, 0, stream>>>(Tb[k % 3], coefs, k, 0, G);
        }
    }
    convert_bf16<<<32768, 256, 0, stream>>>(G, Gb);                 // 8*N*N elems
    convert_bf16<<<512, 256, 0, stream>>>(f, fb);                   // N*DF elems
    mfma_gemm<0><<<dim3(2, 128), 256, 0, stream>>>(Gb, fb, U1b, sum1);
    mfma_gemm<1><<<dim3(16, 128), 256, 0, stream>>>(Gb, U1b, (u16*)nullptr, sum2);
    fmean_kernel<<<1, 256, 0, stream>>>(f, out);
    finalize_kernel<<<64, 256, 0, stream>>>(sum1, sum2, out);
}